// Round 21
// baseline (518.785 us; speedup 1.0000x reference)
//
#include <hip/hip_runtime.h>
#include <hip/hip_bf16.h>

typedef unsigned short u16;
typedef unsigned int   u32;
typedef short bf16x8 __attribute__((ext_vector_type(8)));
typedef float f32x4  __attribute__((ext_vector_type(4)));

#define SS 512
#define XSWZ(g)     ((((g) & 7) << 6) | ((g) >> 3))   // 512-block grids
#define XSWZ1024(g) ((((g) & 7) << 7) | ((g) >> 3))   // 1024-block grids
#define WPREP_STRIDE 22016

#define AS1C(p) ((const __attribute__((address_space(1))) void*)(p))
#define AS3(p)  ((__attribute__((address_space(3))) void*)(p))

// fast erf (Abramowitz-Stegun 7.1.26, |err|<=1.5e-7), branch-free
__device__ __forceinline__ float gelu_f(float v){
    float x  = v * 0.70710678118654752f;
    float ax = fabsf(x);
    float t  = __builtin_amdgcn_rcpf(fmaf(0.3275911f, ax, 1.0f));
    float poly = t*(0.254829592f + t*(-0.284496736f + t*(1.421413741f
               + t*(-1.453152027f + t*1.061405429f))));
    float e  = __expf(-x*x);
    float er = copysignf(1.0f - poly*e, x);
    return 0.5f*v*(1.0f + er);
}
__device__ __forceinline__ u16 bf16_rne(float v){
    u32 u = __float_as_uint(v);
    u32 r = u + 0x7FFF + ((u >> 16) & 1);
    return (u16)(r >> 16);
}
#define DYT(t) ((t)>=9 ? 0 : (t)/3)
#define DXT(t) ((t)>=9 ? 0 : (t)%3)

// ---------- weight prep: split hi/lo into MFMA layout, remap gamma/beta ----------
__global__ __launch_bounds__(256) void k_prep(
    const float* __restrict__ qw, const float* __restrict__ kw,
    const float* __restrict__ vw, const float* __restrict__ cw,
    const float* __restrict__ lng, const float* __restrict__ lnb,
    u16* __restrict__ wprep)
{
    int L = blockIdx.x;
    int tid = threadIdx.x;
    u16* base = wprep + L*WPREP_STRIDE;
    const float* src[4] = {qw + L*2304, kw + L*2304, vw + L*2304, cw + L*2304};
    const int offh[4] = {0, 5120, 10240, 12800};
    const int offl[4] = {2560, 7680, -1, 15360};
    for (int idx = tid; idx < 2304; idx += 256){
        int o = idx / 144, rem = idx - o*144;
        int i = rem / 9, tap = rem - i*9;
        int dst = o*160 + tap*16 + i;
        #pragma unroll
        for (int a = 0; a < 4; ++a){
            float wv = src[a][idx];
            u16 hv = bf16_rne(wv);
            base[offh[a] + dst] = hv;
            if (offl[a] >= 0)
                base[offl[a] + dst] = bf16_rne(wv - __uint_as_float((u32)hv<<16));
        }
    }
    {
        int o = tid >> 4, kk = tid & 15;
        int d = o*160 + 144 + kk;
        base[d]=0; base[2560+d]=0; base[5120+d]=0; base[7680+d]=0;
        base[10240+d]=0; base[12800+d]=0; base[15360+d]=0;
    }
    float* gr = (float*)(base + 17920);
    float* br = (float*)(base + 19968);
    for (int idx = tid; idx < 1024; idx += 256){
        int od = (idx & 15)*64 + (idx >> 4);
        gr[idx] = lng[L*1024 + od];
        br[idx] = lnb[L*1024 + od];
    }
}

// ---------- embedding (padding_idx=0) + layernorm ----------
__global__ __launch_bounds__(256) void k_embed_ln(
    const int* __restrict__ x, const float* __restrict__ emb,
    const float* __restrict__ g, const float* __restrict__ bta,
    float* __restrict__ h, u16* __restrict__ hh, u16* __restrict__ hl)
{
    int bs = blockIdx.x;
    int b = bs >> 9, s = bs & 511;
    int t = x[bs];
    int tid = threadIdx.x;
    float v[4];
    #pragma unroll
    for (int j = 0; j < 4; ++j){
        int idx = tid + j*256;
        v[j] = (t == 0) ? 0.0f : emb[(size_t)t*1024 + idx];
    }
    float sum = v[0]+v[1]+v[2]+v[3];
    float sq  = v[0]*v[0]+v[1]*v[1]+v[2]*v[2]+v[3]*v[3];
    __shared__ float red[2][4];
    int lane = tid & 63, wid = tid >> 6;
    #pragma unroll
    for (int off = 32; off; off >>= 1){
        sum += __shfl_down(sum, off, 64);
        sq  += __shfl_down(sq,  off, 64);
    }
    if (lane == 0){ red[0][wid] = sum; red[1][wid] = sq; }
    __syncthreads();
    sum = red[0][0]+red[0][1]+red[0][2]+red[0][3];
    sq  = red[1][0]+red[1][1]+red[1][2]+red[1][3];
    float mean = sum * (1.0f/1024.0f);
    float var  = sq  * (1.0f/1024.0f) - mean*mean;
    float rs = rsqrtf(var + 1e-5f);
    #pragma unroll
    for (int j = 0; j < 4; ++j){
        int idx = tid + j*256;
        float y = (v[j]-mean)*rs*g[idx] + bta[idx];
        int m = idx >> 6, n = idx & 63;
        h[((size_t)(b*16 + m)*SS + s)*64 + n] = y;
        u16 hv = bf16_rne(y);
        u16 lv = bf16_rne(y - __uint_as_float((u32)hv<<16));
        size_t da = ((size_t)b*SS + s)*1024 + n*16 + m;
        hh[da] = hv; hl[da] = lv;
    }
}

// ---------- fused QKV conv: 256 thr / 8 rows / grid 1024, 2 blocks/CU ----------
// q,k emit hi only (QK^T is pure bf16 qh*kh); v -> vT bf16
__global__ __launch_bounds__(256,2) void k_conv_qkv(
    const u16* __restrict__ inh, const u16* __restrict__ inl,
    const u16* __restrict__ wp,
    const float* __restrict__ qb, const float* __restrict__ kb,
    const float* __restrict__ vb,
    u16* __restrict__ qoh, u16* __restrict__ koh,
    u16* __restrict__ vT)
{
    int bid = XSWZ1024(blockIdx.x);       // 16 b x 64 ytiles
    int b  = bid >> 6;
    int y0 = (bid & 63) * 8;
    int tid = threadIdx.x;
    int w4 = tid >> 6, lane = tid & 63;
    int l15 = lane & 15, l4 = lane >> 4;

    __shared__ u16 shi[10*68*24];
    __shared__ u16 slo[10*68*24];

    if (tid < 40){    // zero x-halo cols
        int y = tid >> 2, rr = tid & 3;
        int tc = (rr >> 1) ? 65 : 0;
        int h8 = (rr & 1) * 8;
        int ad = (y*68 + tc)*24 + h8;
        *(uint4*)&shi[ad] = make_uint4(0,0,0,0);
        *(uint4*)&slo[ad] = make_uint4(0,0,0,0);
    }
    #pragma unroll
    for (int it = 0; it < 5; ++it){
        int idx = tid + it*256;           // 0..1279
        int y = idx >> 7;
        int rem = idx & 127;
        int xx = rem >> 1, h8 = (rem & 1)*8;
        int gy = y0 - 1 + y;
        uint4 vh = make_uint4(0,0,0,0), vl = make_uint4(0,0,0,0);
        if (gy >= 0 && gy < SS){
            size_t ga = ((size_t)b*SS + gy)*1024 + xx*16 + h8;
            vh = *(const uint4*)(inh + ga);
            vl = *(const uint4*)(inl + ga);
        }
        int la = (y*68 + (xx+1))*24 + h8;
        *(uint4*)&shi[la] = vh;
        *(uint4*)&slo[la] = vl;
    }
    __syncthreads();

    bf16x8 aq_h[5], aq_l[5], ak_h[5], ak_l[5], av_h[5];
    #pragma unroll
    for (int p = 0; p < 5; ++p){
        int aad = l15*160 + p*32 + l4*8;
        aq_h[p] = *(const bf16x8*)&wp[aad];
        aq_l[p] = *(const bf16x8*)&wp[2560 + aad];
        ak_h[p] = *(const bf16x8*)&wp[5120 + aad];
        ak_l[p] = *(const bf16x8*)&wp[7680 + aad];
        av_h[p] = *(const bf16x8*)&wp[10240 + aad];
    }

    f32x4 accq[8], acck[8], accv[8];
    #pragma unroll
    for (int i = 0; i < 8; ++i){
        accq[i] = (f32x4){0.f,0.f,0.f,0.f};
        acck[i] = (f32x4){0.f,0.f,0.f,0.f};
        accv[i] = (f32x4){0.f,0.f,0.f,0.f};
    }
    int hsel = l4 >> 1;
    int i0 = (l4 & 1)*8;
    int xo = w4*16 + l15;

    #pragma unroll
    for (int p = 0; p < 5; ++p){
        int dy = hsel ? DYT(2*p+1) : DYT(2*p);
        int dx = hsel ? DXT(2*p+1) : DXT(2*p);
        int badd0 = (dy*68 + xo + dx)*24 + i0;
        #pragma unroll
        for (int yy = 0; yy < 8; ++yy){
            int bad = badd0 + yy*(68*24);
            bf16x8 bh = *(const bf16x8*)&shi[bad];
            bf16x8 bl = *(const bf16x8*)&slo[bad];
            accq[yy] = __builtin_amdgcn_mfma_f32_16x16x32_bf16(aq_h[p], bh, accq[yy],0,0,0);
            accq[yy] = __builtin_amdgcn_mfma_f32_16x16x32_bf16(aq_l[p], bh, accq[yy],0,0,0);
            accq[yy] = __builtin_amdgcn_mfma_f32_16x16x32_bf16(aq_h[p], bl, accq[yy],0,0,0);
            acck[yy] = __builtin_amdgcn_mfma_f32_16x16x32_bf16(ak_h[p], bh, acck[yy],0,0,0);
            acck[yy] = __builtin_amdgcn_mfma_f32_16x16x32_bf16(ak_l[p], bh, acck[yy],0,0,0);
            acck[yy] = __builtin_amdgcn_mfma_f32_16x16x32_bf16(ak_h[p], bl, acck[yy],0,0,0);
            accv[yy] = __builtin_amdgcn_mfma_f32_16x16x32_bf16(av_h[p], bh, accv[yy],0,0,0);
        }
    }

    float qbv[4], kbv[4], vbv[4];
    #pragma unroll
    for (int i = 0; i < 4; ++i){
        qbv[i] = qb[l4*4 + i];
        kbv[i] = kb[l4*4 + i];
        vbv[i] = vb[l4*4 + i];
    }
    union { u16 u[4][8]; uint4 q[4]; } vpk;
    #pragma unroll
    for (int yy = 0; yy < 8; ++yy){
        int y = y0 + yy;
        u16 qh4[4], kh4[4];
        #pragma unroll
        for (int i = 0; i < 4; ++i){
            qh4[i] = bf16_rne(gelu_f(accq[yy][i] + qbv[i]));
            kh4[i] = bf16_rne(gelu_f(acck[yy][i] + kbv[i]));
            vpk.u[i][yy] = bf16_rne(gelu_f(accv[yy][i] + vbv[i]));
        }
        size_t oa = ((size_t)b*SS + y)*1024 + xo*16 + l4*4;
        *(uint2*)&qoh[oa] = make_uint2((u32)qh4[0]|((u32)qh4[1]<<16),(u32)qh4[2]|((u32)qh4[3]<<16));
        *(uint2*)&koh[oa] = make_uint2((u32)kh4[0]|((u32)kh4[1]<<16),(u32)kh4[2]|((u32)kh4[3]<<16));
    }
    #pragma unroll
    for (int i = 0; i < 4; ++i)
        *(uint4*)(vT + ((size_t)b*1024 + xo*16 + l4*4 + i)*SS + y0) = vpk.q[i];
}

// ---------- fused LN+conv+residual: 256 thr / 8 rows / grid 1024, 2 blocks/CU ----------
__global__ __launch_bounds__(256,2) void k_conv_ln_res2(
    const float* __restrict__ o_pre, const float* __restrict__ stats,
    const u16* __restrict__ wp, const float* __restrict__ bias,
    const float* __restrict__ resid, float* __restrict__ outf,
    u16* __restrict__ outh, u16* __restrict__ outl)
{
    int bid = XSWZ1024(blockIdx.x);       // 16 b x 64 ytiles
    int b  = bid >> 6;
    int y0 = (bid & 63) * 8;
    int tid = threadIdx.x;
    int w4 = tid >> 6, lane = tid & 63;
    int l15 = lane & 15, l4 = lane >> 4;

    __shared__ u16 shi[10*68*24];
    __shared__ u16 slo[10*68*24];

    if (tid < 40){    // zero x-halo cols
        int y = tid >> 2, rr = tid & 3;
        int tc = (rr >> 1) ? 65 : 0;
        int h8 = (rr & 1) * 8;
        int ad = (y*68 + tc)*24 + h8;
        *(uint4*)&shi[ad] = make_uint4(0,0,0,0);
        *(uint4*)&slo[ad] = make_uint4(0,0,0,0);
    }
    const float* gr = (const float*)(wp + 17920);
    const float* br = (const float*)(wp + 19968);
    #pragma unroll
    for (int it = 0; it < 5; ++it){
        int idx = tid + it*256;           // 0..1279
        int y = idx >> 7;
        int rem = idx & 127;
        int xx = rem >> 1, h8 = (rem & 1)*8;
        int gy = y0 - 1 + y;
        int la = (y*68 + (xx+1))*24 + h8;
        uint4 ph = make_uint4(0,0,0,0), pl = make_uint4(0,0,0,0);
        if (gy >= 0 && gy < SS){
            float s  = stats[2*((size_t)b*SS + gy)];
            float q  = stats[2*((size_t)b*SS + gy) + 1];
            float mu = s * (1.0f/1024.0f);
            float rs = rsqrtf(q * (1.0f/1024.0f) - mu*mu + 1e-5f);
            int dbase = xx*16 + h8;
            float4 v0 = *(const float4*)(o_pre + ((size_t)b*SS + gy)*1024 + dbase);
            float4 v1 = *(const float4*)(o_pre + ((size_t)b*SS + gy)*1024 + dbase + 4);
            float4 g0 = *(const float4*)&gr[dbase];
            float4 g1 = *(const float4*)&gr[dbase + 4];
            float4 b0 = *(const float4*)&br[dbase];
            float4 b1 = *(const float4*)&br[dbase + 4];
            float va[8] = {v0.x,v0.y,v0.z,v0.w,v1.x,v1.y,v1.z,v1.w};
            float ga[8] = {g0.x,g0.y,g0.z,g0.w,g1.x,g1.y,g1.z,g1.w};
            float ba[8] = {b0.x,b0.y,b0.z,b0.w,b1.x,b1.y,b1.z,b1.w};
            u16 hh8[8], ll8[8];
            #pragma unroll
            for (int j = 0; j < 8; ++j){
                float yv = (va[j] - mu)*rs*ga[j] + ba[j];
                hh8[j] = bf16_rne(yv);
                ll8[j] = bf16_rne(yv - __uint_as_float((u32)hh8[j]<<16));
            }
            ph = make_uint4((u32)hh8[0]|((u32)hh8[1]<<16), (u32)hh8[2]|((u32)hh8[3]<<16),
                            (u32)hh8[4]|((u32)hh8[5]<<16), (u32)hh8[6]|((u32)hh8[7]<<16));
            pl = make_uint4((u32)ll8[0]|((u32)ll8[1]<<16), (u32)ll8[2]|((u32)ll8[3]<<16),
                            (u32)ll8[4]|((u32)ll8[5]<<16), (u32)ll8[6]|((u32)ll8[7]<<16));
        }
        *(uint4*)&shi[la] = ph;
        *(uint4*)&slo[la] = pl;
    }
    __syncthreads();

    bf16x8 ah[5], al[5];
    #pragma unroll
    for (int p = 0; p < 5; ++p){
        int aad = l15*160 + p*32 + l4*8;
        ah[p] = *(const bf16x8*)&wp[12800 + aad];
        al[p] = *(const bf16x8*)&wp[15360 + aad];
    }

    f32x4 acc[8];
    #pragma unroll
    for (int i = 0; i < 8; ++i) acc[i] = (f32x4){0.f,0.f,0.f,0.f};
    int hsel = l4 >> 1;
    int i0 = (l4 & 1)*8;
    int xo = w4*16 + l15;

    #pragma unroll
    for (int p = 0; p < 5; ++p){
        int dy = hsel ? DYT(2*p+1) : DYT(2*p);
        int dx = hsel ? DXT(2*p+1) : DXT(2*p);
        int badd0 = (dy*68 + xo + dx)*24 + i0;
        #pragma unroll
        for (int yy = 0; yy < 8; ++yy){
            int bad = badd0 + yy*(68*24);
            bf16x8 bh = *(const bf16x8*)&shi[bad];
            bf16x8 bl = *(const bf16x8*)&slo[bad];
            acc[yy] = __builtin_amdgcn_mfma_f32_16x16x32_bf16(ah[p], bh, acc[yy],0,0,0);
            acc[yy] = __builtin_amdgcn_mfma_f32_16x16x32_bf16(al[p], bh, acc[yy],0,0,0);
            acc[yy] = __builtin_amdgcn_mfma_f32_16x16x32_bf16(ah[p], bl, acc[yy],0,0,0);
        }
    }

    float bv[4];
    #pragma unroll
    for (int i = 0; i < 4; ++i) bv[i] = bias[l4*4 + i];
    #pragma unroll
    for (int yy = 0; yy < 8; ++yy){
        int y = y0 + yy;
        float r[4];
        #pragma unroll
        for (int i = 0; i < 4; ++i) r[i] = gelu_f(acc[yy][i] + bv[i]);
        #pragma unroll
        for (int i = 0; i < 4; ++i){
            int o = l4*4 + i;
            size_t fa = ((size_t)(b*16 + o)*SS + y)*64 + xo;
            float hv = resid[fa] + r[i];
            outf[fa] = hv;
            r[i] = hv;
        }
        u16 hh_[4], ll_[4];
        #pragma unroll
        for (int i = 0; i < 4; ++i){
            hh_[i] = bf16_rne(r[i]);
            ll_[i] = bf16_rne(r[i] - __uint_as_float((u32)hh_[i]<<16));
        }
        size_t oa = ((size_t)b*SS + y)*1024 + xo*16 + l4*4;
        *(uint2*)&outh[oa] = make_uint2((u32)hh_[0]|((u32)hh_[1]<<16),(u32)hh_[2]|((u32)hh_[3]<<16));
        *(uint2*)&outl[oa] = make_uint2((u32)ll_[0]|((u32)ll_[1]<<16),(u32)ll_[2]|((u32)ll_[3]<<16));
    }
}

// ---------- QK^T: 128x64 tiles, gload_lds staging, pure bf16 (1 MFMA) ----------
__global__ __launch_bounds__(256) void k_qk_mfma(
    const u16* __restrict__ qh, const u16* __restrict__ kh,
    float* __restrict__ score)
{
    int bid = XSWZ(blockIdx.x);           // 16b x 4 s1t x 8 s2t = 512
    int b = bid >> 5;
    int s1_0 = ((bid >> 3) & 3) * 128;
    int s2_0 = (bid & 7) * 64;
    __shared__ u16 Ah[128*64], Bh[64*64];
    int tid = threadIdx.x;
    int w = tid >> 6, lane = tid & 63;
    int l15 = lane & 15, l4 = lane >> 4;
    f32x4 acc[2][4];
    #pragma unroll
    for (int r=0;r<2;++r)
        #pragma unroll
        for(int c=0;c<4;++c) acc[r][c] = (f32x4){0.f,0.f,0.f,0.f};

    for (int oc = 0; oc < 16; ++oc){
        size_t qbase = ((size_t)b*SS + s1_0)*1024 + oc*64;
        size_t kbase = ((size_t)b*SS + s2_0)*1024 + oc*64;
        #pragma unroll
        for (int i = 0; i < 4; ++i){
            int idx = tid + i*256;
            int r = idx >> 3, f = idx & 7;
            int fs = f ^ (r & 7);
            __builtin_amdgcn_global_load_lds(AS1C(qh + qbase + (size_t)r*1024 + fs*8),
                                             AS3(&Ah[idx*8]), 16, 0, 0);
        }
        #pragma unroll
        for (int i = 0; i < 2; ++i){
            int idx = tid + i*256;
            int r = idx >> 3, f = idx & 7;
            int fs = f ^ (r & 7);
            __builtin_amdgcn_global_load_lds(AS1C(kh + kbase + (size_t)r*1024 + fs*8),
                                             AS3(&Bh[idx*8]), 16, 0, 0);
        }
        __syncthreads();
        #pragma unroll
        for (int ks = 0; ks < 2; ++ks){
            bf16x8 a_h[2];
            #pragma unroll
            for (int r=0;r<2;++r){
                int row = w*32 + r*16 + l15;
                int ad = row*64 + (((ks*4 + l4) ^ (row & 7))*8);
                a_h[r] = *(const bf16x8*)&Ah[ad];
            }
            #pragma unroll
            for (int c=0;c<4;++c){
                int row = c*16 + l15;
                int bd = row*64 + (((ks*4 + l4) ^ (row & 7))*8);
                bf16x8 b_h = *(const bf16x8*)&Bh[bd];
                #pragma unroll
                for (int r=0;r<2;++r)
                    acc[r][c] = __builtin_amdgcn_mfma_f32_16x16x32_bf16(a_h[r], b_h, acc[r][c],0,0,0);
            }
        }
        __syncthreads();
    }
    #pragma unroll
    for (int r=0;r<2;++r)
        #pragma unroll
        for (int c=0;c<4;++c)
            #pragma unroll
            for (int i=0;i<4;++i){
                int s1 = s1_0 + w*32 + r*16 + l4*4 + i;
                int s2 = s2_0 + c*16 + l15;
                score[((size_t)b*SS + s1)*SS + s2] = acc[r][c][i];
            }
}

// ---------- softmax over batch axis; writes bf16 probs; zeroes stats ----------
__global__ __launch_bounds__(256) void k_softmax_b(
    const float* __restrict__ score, u16* __restrict__ scb,
    float* __restrict__ stats)
{
    int sid = blockIdx.x*256 + threadIdx.x;
    if (sid < 16384) stats[sid] = 0.0f;
    float vals[16];
    float m = -1e30f;
    #pragma unroll
    for (int b = 0; b < 16; ++b){
        vals[b] = score[(size_t)b*SS*SS + sid];
        m = fmaxf(m, vals[b]);
    }
    float sum = 0.f;
    #pragma unroll
    for (int b = 0; b < 16; ++b){ vals[b] = __expf(vals[b]-m); sum += vals[b]; }
    float inv = 1.0f/sum;
    #pragma unroll
    for (int b = 0; b < 16; ++b) scb[(size_t)b*SS*SS + sid] = bf16_rne(vals[b]*inv);
}

// ---------- o_pre = P*vT (128x128), gload_lds staging + fused LN stats ----------
__global__ __launch_bounds__(256) void k_sv_mfma(
    const u16* __restrict__ scb, const u16* __restrict__ vT,
    float* __restrict__ o, float* __restrict__ stats)
{
    int bid = XSWZ(blockIdx.x);           // 16b x 4 s1t x 8 dt = 512
    int b = bid >> 5;
    int s1_0 = ((bid >> 3) & 3) * 128;
    int d0 = (bid & 7) * 128;
    __shared__ u16 As[128*64], Bs[128*64];
    int tid = threadIdx.x;
    int w = tid >> 6, lane = tid & 63;
    int l15 = lane & 15, l4 = lane >> 4;
    f32x4 acc[2][8];
    #pragma unroll
    for (int r=0;r<2;++r)
        #pragma unroll
        for(int c=0;c<8;++c) acc[r][c] = (f32x4){0.f,0.f,0.f,0.f};

    const u16* aBase = scb + ((size_t)b*SS + s1_0)*SS;
    const u16* bBase = vT + ((size_t)b*1024 + d0)*SS;
    for (int st = 0; st < 8; ++st){
        int s2b = st*64;
        #pragma unroll
        for (int i = 0; i < 4; ++i){
            int idx = tid + i*256;
            int r = idx >> 3, f = idx & 7;
            int fs = f ^ (r & 7);
            __builtin_amdgcn_global_load_lds(AS1C(aBase + (size_t)r*SS + s2b + fs*8),
                                             AS3(&As[idx*8]), 16, 0, 0);
            __builtin_amdgcn_global_load_lds(AS1C(bBase + (size_t)r*SS + s2b + fs*8),
                                             AS3(&Bs[idx*8]), 16, 0, 0);
        }
        __syncthreads();
        #pragma unroll
        for (int ks = 0; ks < 2; ++ks){
            bf16x8 a0[2];
            #pragma unroll
            for (int r=0;r<2;++r){
                int row = w*32 + r*16 + l15;
                a0[r] = *(const bf16x8*)&As[row*64 + (((ks*4 + l4) ^ (row & 7))*8)];
            }
            #pragma unroll
            for (int c=0;c<8;++c){
                int row = c*16 + l15;
                bf16x8 b0 = *(const bf16x8*)&Bs[row*64 + (((ks*4 + l4) ^ (row & 7))*8)];
                #pragma unroll
                for (int r=0;r<2;++r)
                    acc[r][c] = __builtin_amdgcn_mfma_f32_16x16x32_bf16(a0[r], b0, acc[r][c],0,0,0);
            }
        }
        __syncthreads();
    }
    #pragma unroll
    for (int r=0;r<2;++r)
        #pragma unroll
        for (int c=0;c<8;++c)
            #pragma unroll
            for (int i=0;i<4;++i){
                int s1 = s1_0 + w*32 + r*16 + l4*4 + i;
                o[((size_t)b*SS + s1)*1024 + d0 + c*16 + l15] = acc[r][c][i];
            }

    #pragma unroll
    for (int r=0;r<2;++r){
        #pragma unroll
        for (int i=0;i<4;++i){
            float s = 0.f, q = 0.f;
            #pragma unroll
            for (int c=0;c<8;++c){ float v = acc[r][c][i]; s += v; q += v*v; }
            #pragma unroll
            for (int m = 1; m <= 8; m <<= 1){
                s += __shfl_xor(s, m, 64);
                q += __shfl_xor(q, m, 64);
            }
            if (l15 == 0){
                int s1 = s1_0 + w*32 + r*16 + l4*4 + i;
                atomicAdd(&stats[2*((size_t)b*SS + s1)],     s);
                atomicAdd(&stats[2*((size_t)b*SS + s1) + 1], q);
            }
        }
    }
}

extern "C" void kernel_launch(void* const* d_in, const int* in_sizes, int n_in,
                              void* d_out, int out_size, void* d_ws, size_t ws_size,
                              hipStream_t stream)
{
    const int*   x    = (const int*)  d_in[0];
    const float* emb  = (const float*)d_in[1];
    const float* g0   = (const float*)d_in[2];
    const float* b0   = (const float*)d_in[3];
    const float* qw   = (const float*)d_in[4];
    const float* qb   = (const float*)d_in[5];
    const float* kw   = (const float*)d_in[6];
    const float* kb   = (const float*)d_in[7];
    const float* vw   = (const float*)d_in[8];
    const float* vb_  = (const float*)d_in[9];
    const float* lng  = (const float*)d_in[10];
    const float* lnb  = (const float*)d_in[11];
    const float* cw   = (const float*)d_in[12];
    const float* cb   = (const float*)d_in[13];
    float* out = (float*)d_out;

    const size_t TS = (size_t)16*16*512*64;       // 8388608
    u16* wsu = (u16*)d_ws;
    u16* hh = wsu + 0*TS;
    u16* hl = wsu + 1*TS;
    u16* qh = wsu + 2*TS;
    u16* ql = wsu + 3*TS;                         // hosts stats head only
    u16* kh = wsu + 4*TS;
    u16* kl = wsu + 5*TS;                         // unused now
    u16* vT = wsu + 6*TS;
    float* sc    = (float*)(wsu + 7*TS);          // 16*512*512 f32 = 1 slot
    u16*   scb   = qh;                            // qh dead after qk
    float* o_pre = (float*)(wsu + 4*TS);          // kh dead after qk
    float* stats = (float*)ql;                    // ql slot head (16384 f32)
    u16* wprep = (u16*)((char*)d_ws + ((size_t)160 << 20));  // ws 640 MiB; prep at 160 MiB

    float* hbuf[5];
    hbuf[0] = out + 1*TS;
    hbuf[1] = out + 2*TS;
    hbuf[2] = out + 3*TS;
    hbuf[3] = out + 4*TS;
    hbuf[4] = out;

    k_prep<<<4, 256, 0, stream>>>(qw, kw, vw, cw, lng, lnb, wprep);
    k_embed_ln<<<8192, 256, 0, stream>>>(x, emb, g0, b0, hbuf[0], hh, hl);
    for (int i = 0; i < 4; ++i){
        const u16* wp = wprep + i*WPREP_STRIDE;
        k_conv_qkv<<<1024, 256, 0, stream>>>(
            hh, hl, wp, qb + i*16, kb + i*16, vb_ + i*16, qh, kh, vT);
        k_qk_mfma<<<512, 256, 0, stream>>>(qh, kh, sc);
        k_softmax_b<<<1024, 256, 0, stream>>>(sc, scb, stats);
        k_sv_mfma<<<512, 256, 0, stream>>>(scb, vT, o_pre, stats);
        k_conv_ln_res2<<<1024, 256, 0, stream>>>(
            o_pre, stats, wp, cb + i*16, hbuf[i], hbuf[i+1], hh, hl);
    }
}

// Round 22
// 499.730 us; speedup vs baseline: 1.0381x; 1.0381x over previous
//
#include <hip/hip_runtime.h>
#include <hip/hip_bf16.h>

typedef unsigned short u16;
typedef unsigned int   u32;
typedef short bf16x8 __attribute__((ext_vector_type(8)));
typedef float f32x4  __attribute__((ext_vector_type(4)));

#define SS 512
#define XSWZ(g)     ((((g) & 7) << 6) | ((g) >> 3))   // 512-block grids
#define XSWZ1024(g) ((((g) & 7) << 7) | ((g) >> 3))   // 1024-block grids
#define WPREP_STRIDE 22016

#define AS1C(p) ((const __attribute__((address_space(1))) void*)(p))
#define AS3(p)  ((__attribute__((address_space(3))) void*)(p))

// fast erf (Abramowitz-Stegun 7.1.26, |err|<=1.5e-7), branch-free
__device__ __forceinline__ float gelu_f(float v){
    float x  = v * 0.70710678118654752f;
    float ax = fabsf(x);
    float t  = __builtin_amdgcn_rcpf(fmaf(0.3275911f, ax, 1.0f));
    float poly = t*(0.254829592f + t*(-0.284496736f + t*(1.421413741f
               + t*(-1.453152027f + t*1.061405429f))));
    float e  = __expf(-x*x);
    float er = copysignf(1.0f - poly*e, x);
    return 0.5f*v*(1.0f + er);
}
__device__ __forceinline__ u16 bf16_rne(float v){
    u32 u = __float_as_uint(v);
    u32 r = u + 0x7FFF + ((u >> 16) & 1);
    return (u16)(r >> 16);
}
#define DYT(t) ((t)>=9 ? 0 : (t)/3)
#define DXT(t) ((t)>=9 ? 0 : (t)%3)

// ---------- weight prep: split hi/lo into MFMA layout, remap gamma/beta ----------
__global__ __launch_bounds__(256) void k_prep(
    const float* __restrict__ qw, const float* __restrict__ kw,
    const float* __restrict__ vw, const float* __restrict__ cw,
    const float* __restrict__ lng, const float* __restrict__ lnb,
    u16* __restrict__ wprep)
{
    int L = blockIdx.x;
    int tid = threadIdx.x;
    u16* base = wprep + L*WPREP_STRIDE;
    const float* src[4] = {qw + L*2304, kw + L*2304, vw + L*2304, cw + L*2304};
    const int offh[4] = {0, 5120, 10240, 12800};
    const int offl[4] = {2560, 7680, -1, 15360};
    for (int idx = tid; idx < 2304; idx += 256){
        int o = idx / 144, rem = idx - o*144;
        int i = rem / 9, tap = rem - i*9;
        int dst = o*160 + tap*16 + i;
        #pragma unroll
        for (int a = 0; a < 4; ++a){
            float wv = src[a][idx];
            u16 hv = bf16_rne(wv);
            base[offh[a] + dst] = hv;
            if (offl[a] >= 0)
                base[offl[a] + dst] = bf16_rne(wv - __uint_as_float((u32)hv<<16));
        }
    }
    {
        int o = tid >> 4, kk = tid & 15;
        int d = o*160 + 144 + kk;
        base[d]=0; base[2560+d]=0; base[5120+d]=0; base[7680+d]=0;
        base[10240+d]=0; base[12800+d]=0; base[15360+d]=0;
    }
    float* gr = (float*)(base + 17920);
    float* br = (float*)(base + 19968);
    for (int idx = tid; idx < 1024; idx += 256){
        int od = (idx & 15)*64 + (idx >> 4);
        gr[idx] = lng[L*1024 + od];
        br[idx] = lnb[L*1024 + od];
    }
}

// ---------- embedding (padding_idx=0) + layernorm ----------
__global__ __launch_bounds__(256) void k_embed_ln(
    const int* __restrict__ x, const float* __restrict__ emb,
    const float* __restrict__ g, const float* __restrict__ bta,
    float* __restrict__ h, u16* __restrict__ hh, u16* __restrict__ hl)
{
    int bs = blockIdx.x;
    int b = bs >> 9, s = bs & 511;
    int t = x[bs];
    int tid = threadIdx.x;
    float v[4];
    #pragma unroll
    for (int j = 0; j < 4; ++j){
        int idx = tid + j*256;
        v[j] = (t == 0) ? 0.0f : emb[(size_t)t*1024 + idx];
    }
    float sum = v[0]+v[1]+v[2]+v[3];
    float sq  = v[0]*v[0]+v[1]*v[1]+v[2]*v[2]+v[3]*v[3];
    __shared__ float red[2][4];
    int lane = tid & 63, wid = tid >> 6;
    #pragma unroll
    for (int off = 32; off; off >>= 1){
        sum += __shfl_down(sum, off, 64);
        sq  += __shfl_down(sq,  off, 64);
    }
    if (lane == 0){ red[0][wid] = sum; red[1][wid] = sq; }
    __syncthreads();
    sum = red[0][0]+red[0][1]+red[0][2]+red[0][3];
    sq  = red[1][0]+red[1][1]+red[1][2]+red[1][3];
    float mean = sum * (1.0f/1024.0f);
    float var  = sq  * (1.0f/1024.0f) - mean*mean;
    float rs = rsqrtf(var + 1e-5f);
    #pragma unroll
    for (int j = 0; j < 4; ++j){
        int idx = tid + j*256;
        float y = (v[j]-mean)*rs*g[idx] + bta[idx];
        int m = idx >> 6, n = idx & 63;
        h[((size_t)(b*16 + m)*SS + s)*64 + n] = y;
        u16 hv = bf16_rne(y);
        u16 lv = bf16_rne(y - __uint_as_float((u32)hv<<16));
        size_t da = ((size_t)b*SS + s)*1024 + n*16 + m;
        hh[da] = hv; hl[da] = lv;
    }
}

// ---------- fused QKV conv: 256 thr / 8 rows / grid 1024, 2 blocks/CU ----------
// q emits hi only; k emits hi/lo; v -> vT bf16
__global__ __launch_bounds__(256,2) void k_conv_qkv(
    const u16* __restrict__ inh, const u16* __restrict__ inl,
    const u16* __restrict__ wp,
    const float* __restrict__ qb, const float* __restrict__ kb,
    const float* __restrict__ vb,
    u16* __restrict__ qoh,
    u16* __restrict__ koh, u16* __restrict__ kol,
    u16* __restrict__ vT)
{
    int bid = XSWZ1024(blockIdx.x);       // 16 b x 64 ytiles
    int b  = bid >> 6;
    int y0 = (bid & 63) * 8;
    int tid = threadIdx.x;
    int w4 = tid >> 6, lane = tid & 63;
    int l15 = lane & 15, l4 = lane >> 4;

    __shared__ u16 shi[10*68*24];
    __shared__ u16 slo[10*68*24];

    if (tid < 40){    // zero x-halo cols
        int y = tid >> 2, rr = tid & 3;
        int tc = (rr >> 1) ? 65 : 0;
        int h8 = (rr & 1) * 8;
        int ad = (y*68 + tc)*24 + h8;
        *(uint4*)&shi[ad] = make_uint4(0,0,0,0);
        *(uint4*)&slo[ad] = make_uint4(0,0,0,0);
    }
    #pragma unroll
    for (int it = 0; it < 5; ++it){
        int idx = tid + it*256;           // 0..1279
        int y = idx >> 7;
        int rem = idx & 127;
        int xx = rem >> 1, h8 = (rem & 1)*8;
        int gy = y0 - 1 + y;
        uint4 vh = make_uint4(0,0,0,0), vl = make_uint4(0,0,0,0);
        if (gy >= 0 && gy < SS){
            size_t ga = ((size_t)b*SS + gy)*1024 + xx*16 + h8;
            vh = *(const uint4*)(inh + ga);
            vl = *(const uint4*)(inl + ga);
        }
        int la = (y*68 + (xx+1))*24 + h8;
        *(uint4*)&shi[la] = vh;
        *(uint4*)&slo[la] = vl;
    }
    __syncthreads();

    bf16x8 aq_h[5], aq_l[5], ak_h[5], ak_l[5], av_h[5];
    #pragma unroll
    for (int p = 0; p < 5; ++p){
        int aad = l15*160 + p*32 + l4*8;
        aq_h[p] = *(const bf16x8*)&wp[aad];
        aq_l[p] = *(const bf16x8*)&wp[2560 + aad];
        ak_h[p] = *(const bf16x8*)&wp[5120 + aad];
        ak_l[p] = *(const bf16x8*)&wp[7680 + aad];
        av_h[p] = *(const bf16x8*)&wp[10240 + aad];
    }

    f32x4 accq[8], acck[8], accv[8];
    #pragma unroll
    for (int i = 0; i < 8; ++i){
        accq[i] = (f32x4){0.f,0.f,0.f,0.f};
        acck[i] = (f32x4){0.f,0.f,0.f,0.f};
        accv[i] = (f32x4){0.f,0.f,0.f,0.f};
    }
    int hsel = l4 >> 1;
    int i0 = (l4 & 1)*8;
    int xo = w4*16 + l15;

    #pragma unroll
    for (int p = 0; p < 5; ++p){
        int dy = hsel ? DYT(2*p+1) : DYT(2*p);
        int dx = hsel ? DXT(2*p+1) : DXT(2*p);
        int badd0 = (dy*68 + xo + dx)*24 + i0;
        #pragma unroll
        for (int yy = 0; yy < 8; ++yy){
            int bad = badd0 + yy*(68*24);
            bf16x8 bh = *(const bf16x8*)&shi[bad];
            bf16x8 bl = *(const bf16x8*)&slo[bad];
            accq[yy] = __builtin_amdgcn_mfma_f32_16x16x32_bf16(aq_h[p], bh, accq[yy],0,0,0);
            accq[yy] = __builtin_amdgcn_mfma_f32_16x16x32_bf16(aq_l[p], bh, accq[yy],0,0,0);
            accq[yy] = __builtin_amdgcn_mfma_f32_16x16x32_bf16(aq_h[p], bl, accq[yy],0,0,0);
            acck[yy] = __builtin_amdgcn_mfma_f32_16x16x32_bf16(ak_h[p], bh, acck[yy],0,0,0);
            acck[yy] = __builtin_amdgcn_mfma_f32_16x16x32_bf16(ak_l[p], bh, acck[yy],0,0,0);
            acck[yy] = __builtin_amdgcn_mfma_f32_16x16x32_bf16(ak_h[p], bl, acck[yy],0,0,0);
            accv[yy] = __builtin_amdgcn_mfma_f32_16x16x32_bf16(av_h[p], bh, accv[yy],0,0,0);
        }
    }

    float qbv[4], kbv[4], vbv[4];
    #pragma unroll
    for (int i = 0; i < 4; ++i){
        qbv[i] = qb[l4*4 + i];
        kbv[i] = kb[l4*4 + i];
        vbv[i] = vb[l4*4 + i];
    }
    union { u16 u[4][8]; uint4 q[4]; } vpk;
    #pragma unroll
    for (int yy = 0; yy < 8; ++yy){
        int y = y0 + yy;
        u16 qh4[4], kh4[4], kl4[4];
        #pragma unroll
        for (int i = 0; i < 4; ++i){
            float vq = gelu_f(accq[yy][i] + qbv[i]);
            qh4[i] = bf16_rne(vq);
            float vk = gelu_f(acck[yy][i] + kbv[i]);
            u16 kv = bf16_rne(vk);
            kh4[i] = kv; kl4[i] = bf16_rne(vk - __uint_as_float((u32)kv<<16));
            vpk.u[i][yy] = bf16_rne(gelu_f(accv[yy][i] + vbv[i]));
        }
        size_t oa = ((size_t)b*SS + y)*1024 + xo*16 + l4*4;
        *(uint2*)&qoh[oa] = make_uint2((u32)qh4[0]|((u32)qh4[1]<<16),(u32)qh4[2]|((u32)qh4[3]<<16));
        *(uint2*)&koh[oa] = make_uint2((u32)kh4[0]|((u32)kh4[1]<<16),(u32)kh4[2]|((u32)kh4[3]<<16));
        *(uint2*)&kol[oa] = make_uint2((u32)kl4[0]|((u32)kl4[1]<<16),(u32)kl4[2]|((u32)kl4[3]<<16));
    }
    #pragma unroll
    for (int i = 0; i < 4; ++i)
        *(uint4*)(vT + ((size_t)b*1024 + xo*16 + l4*4 + i)*SS + y0) = vpk.q[i];
}

// ---------- fused LN+conv+residual: 256 thr / 8 rows / grid 1024, 2 blocks/CU ----------
__global__ __launch_bounds__(256,2) void k_conv_ln_res2(
    const float* __restrict__ o_pre, const float* __restrict__ stats,
    const u16* __restrict__ wp, const float* __restrict__ bias,
    const float* __restrict__ resid, float* __restrict__ outf,
    u16* __restrict__ outh, u16* __restrict__ outl)
{
    int bid = XSWZ1024(blockIdx.x);       // 16 b x 64 ytiles
    int b  = bid >> 6;
    int y0 = (bid & 63) * 8;
    int tid = threadIdx.x;
    int w4 = tid >> 6, lane = tid & 63;
    int l15 = lane & 15, l4 = lane >> 4;

    __shared__ u16 shi[10*68*24];
    __shared__ u16 slo[10*68*24];

    if (tid < 40){    // zero x-halo cols
        int y = tid >> 2, rr = tid & 3;
        int tc = (rr >> 1) ? 65 : 0;
        int h8 = (rr & 1) * 8;
        int ad = (y*68 + tc)*24 + h8;
        *(uint4*)&shi[ad] = make_uint4(0,0,0,0);
        *(uint4*)&slo[ad] = make_uint4(0,0,0,0);
    }
    const float* gr = (const float*)(wp + 17920);
    const float* br = (const float*)(wp + 19968);
    #pragma unroll
    for (int it = 0; it < 5; ++it){
        int idx = tid + it*256;           // 0..1279
        int y = idx >> 7;
        int rem = idx & 127;
        int xx = rem >> 1, h8 = (rem & 1)*8;
        int gy = y0 - 1 + y;
        int la = (y*68 + (xx+1))*24 + h8;
        uint4 ph = make_uint4(0,0,0,0), pl = make_uint4(0,0,0,0);
        if (gy >= 0 && gy < SS){
            float s  = stats[2*((size_t)b*SS + gy)];
            float q  = stats[2*((size_t)b*SS + gy) + 1];
            float mu = s * (1.0f/1024.0f);
            float rs = rsqrtf(q * (1.0f/1024.0f) - mu*mu + 1e-5f);
            int dbase = xx*16 + h8;
            float4 v0 = *(const float4*)(o_pre + ((size_t)b*SS + gy)*1024 + dbase);
            float4 v1 = *(const float4*)(o_pre + ((size_t)b*SS + gy)*1024 + dbase + 4);
            float4 g0 = *(const float4*)&gr[dbase];
            float4 g1 = *(const float4*)&gr[dbase + 4];
            float4 b0 = *(const float4*)&br[dbase];
            float4 b1 = *(const float4*)&br[dbase + 4];
            float va[8] = {v0.x,v0.y,v0.z,v0.w,v1.x,v1.y,v1.z,v1.w};
            float ga[8] = {g0.x,g0.y,g0.z,g0.w,g1.x,g1.y,g1.z,g1.w};
            float ba[8] = {b0.x,b0.y,b0.z,b0.w,b1.x,b1.y,b1.z,b1.w};
            u16 hh8[8], ll8[8];
            #pragma unroll
            for (int j = 0; j < 8; ++j){
                float yv = (va[j] - mu)*rs*ga[j] + ba[j];
                hh8[j] = bf16_rne(yv);
                ll8[j] = bf16_rne(yv - __uint_as_float((u32)hh8[j]<<16));
            }
            ph = make_uint4((u32)hh8[0]|((u32)hh8[1]<<16), (u32)hh8[2]|((u32)hh8[3]<<16),
                            (u32)hh8[4]|((u32)hh8[5]<<16), (u32)hh8[6]|((u32)hh8[7]<<16));
            pl = make_uint4((u32)ll8[0]|((u32)ll8[1]<<16), (u32)ll8[2]|((u32)ll8[3]<<16),
                            (u32)ll8[4]|((u32)ll8[5]<<16), (u32)ll8[6]|((u32)ll8[7]<<16));
        }
        *(uint4*)&shi[la] = ph;
        *(uint4*)&slo[la] = pl;
    }
    __syncthreads();

    bf16x8 ah[5], al[5];
    #pragma unroll
    for (int p = 0; p < 5; ++p){
        int aad = l15*160 + p*32 + l4*8;
        ah[p] = *(const bf16x8*)&wp[12800 + aad];
        al[p] = *(const bf16x8*)&wp[15360 + aad];
    }

    f32x4 acc[8];
    #pragma unroll
    for (int i = 0; i < 8; ++i) acc[i] = (f32x4){0.f,0.f,0.f,0.f};
    int hsel = l4 >> 1;
    int i0 = (l4 & 1)*8;
    int xo = w4*16 + l15;

    #pragma unroll
    for (int p = 0; p < 5; ++p){
        int dy = hsel ? DYT(2*p+1) : DYT(2*p);
        int dx = hsel ? DXT(2*p+1) : DXT(2*p);
        int badd0 = (dy*68 + xo + dx)*24 + i0;
        #pragma unroll
        for (int yy = 0; yy < 8; ++yy){
            int bad = badd0 + yy*(68*24);
            bf16x8 bh = *(const bf16x8*)&shi[bad];
            bf16x8 bl = *(const bf16x8*)&slo[bad];
            acc[yy] = __builtin_amdgcn_mfma_f32_16x16x32_bf16(ah[p], bh, acc[yy],0,0,0);
            acc[yy] = __builtin_amdgcn_mfma_f32_16x16x32_bf16(al[p], bh, acc[yy],0,0,0);
            acc[yy] = __builtin_amdgcn_mfma_f32_16x16x32_bf16(ah[p], bl, acc[yy],0,0,0);
        }
    }

    float bv[4];
    #pragma unroll
    for (int i = 0; i < 4; ++i) bv[i] = bias[l4*4 + i];
    #pragma unroll
    for (int yy = 0; yy < 8; ++yy){
        int y = y0 + yy;
        float r[4];
        #pragma unroll
        for (int i = 0; i < 4; ++i) r[i] = gelu_f(acc[yy][i] + bv[i]);
        #pragma unroll
        for (int i = 0; i < 4; ++i){
            int o = l4*4 + i;
            size_t fa = ((size_t)(b*16 + o)*SS + y)*64 + xo;
            float hv = resid[fa] + r[i];
            outf[fa] = hv;
            r[i] = hv;
        }
        u16 hh_[4], ll_[4];
        #pragma unroll
        for (int i = 0; i < 4; ++i){
            hh_[i] = bf16_rne(r[i]);
            ll_[i] = bf16_rne(r[i] - __uint_as_float((u32)hh_[i]<<16));
        }
        size_t oa = ((size_t)b*SS + y)*1024 + xo*16 + l4*4;
        *(uint2*)&outh[oa] = make_uint2((u32)hh_[0]|((u32)hh_[1]<<16),(u32)hh_[2]|((u32)hh_[3]<<16));
        *(uint2*)&outl[oa] = make_uint2((u32)ll_[0]|((u32)ll_[1]<<16),(u32)ll_[2]|((u32)ll_[3]<<16));
    }
}

// ---------- QK^T: 128x64 tiles, gload_lds, K=128 per stage (half the barriers) ----------
__global__ __launch_bounds__(256) void k_qk_mfma(
    const u16* __restrict__ qh, const u16* __restrict__ kh,
    const u16* __restrict__ kl, float* __restrict__ score)
{
    int bid = XSWZ(blockIdx.x);           // 16b x 4 s1t x 8 s2t = 512
    int b = bid >> 5;
    int s1_0 = ((bid >> 3) & 3) * 128;
    int s2_0 = (bid & 7) * 64;
    __shared__ u16 Ah[2*128*64], Bh[2*64*64], Bl[2*64*64];
    int tid = threadIdx.x;
    int w = tid >> 6, lane = tid & 63;
    int l15 = lane & 15, l4 = lane >> 4;
    f32x4 acc[2][4];
    #pragma unroll
    for (int r=0;r<2;++r)
        #pragma unroll
        for(int c=0;c<4;++c) acc[r][c] = (f32x4){0.f,0.f,0.f,0.f};

    size_t qbase0 = ((size_t)b*SS + s1_0)*1024;
    size_t kbase0 = ((size_t)b*SS + s2_0)*1024;

    for (int oc = 0; oc < 16; oc += 2){
        #pragma unroll
        for (int hhf = 0; hhf < 2; ++hhf){
            size_t qb2 = qbase0 + (size_t)(oc + hhf)*64;
            size_t kb2 = kbase0 + (size_t)(oc + hhf)*64;
            #pragma unroll
            for (int i = 0; i < 4; ++i){
                int idx = tid + i*256;
                int r = idx >> 3, f = idx & 7;
                int fs = f ^ (r & 7);
                __builtin_amdgcn_global_load_lds(AS1C(qh + qb2 + (size_t)r*1024 + fs*8),
                                                 AS3(&Ah[hhf*128*64 + idx*8]), 16, 0, 0);
            }
            #pragma unroll
            for (int i = 0; i < 2; ++i){
                int idx = tid + i*256;
                int r = idx >> 3, f = idx & 7;
                int fs = f ^ (r & 7);
                size_t sa = kb2 + (size_t)r*1024 + fs*8;
                __builtin_amdgcn_global_load_lds(AS1C(kh + sa), AS3(&Bh[hhf*64*64 + idx*8]), 16, 0, 0);
                __builtin_amdgcn_global_load_lds(AS1C(kl + sa), AS3(&Bl[hhf*64*64 + idx*8]), 16, 0, 0);
            }
        }
        __syncthreads();
        #pragma unroll
        for (int hhf = 0; hhf < 2; ++hhf){
            #pragma unroll
            for (int ks = 0; ks < 2; ++ks){
                bf16x8 a_h[2];
                #pragma unroll
                for (int r=0;r<2;++r){
                    int row = w*32 + r*16 + l15;
                    int ad = hhf*128*64 + row*64 + (((ks*4 + l4) ^ (row & 7))*8);
                    a_h[r] = *(const bf16x8*)&Ah[ad];
                }
                #pragma unroll
                for (int c=0;c<4;++c){
                    int row = c*16 + l15;
                    int bd = hhf*64*64 + row*64 + (((ks*4 + l4) ^ (row & 7))*8);
                    bf16x8 b_h = *(const bf16x8*)&Bh[bd];
                    bf16x8 b_l = *(const bf16x8*)&Bl[bd];
                    #pragma unroll
                    for (int r=0;r<2;++r){
                        acc[r][c] = __builtin_amdgcn_mfma_f32_16x16x32_bf16(a_h[r], b_h, acc[r][c],0,0,0);
                        acc[r][c] = __builtin_amdgcn_mfma_f32_16x16x32_bf16(a_h[r], b_l, acc[r][c],0,0,0);
                    }
                }
            }
        }
        __syncthreads();
    }
    #pragma unroll
    for (int r=0;r<2;++r)
        #pragma unroll
        for (int c=0;c<4;++c)
            #pragma unroll
            for (int i=0;i<4;++i){
                int s1 = s1_0 + w*32 + r*16 + l4*4 + i;
                int s2 = s2_0 + c*16 + l15;
                score[((size_t)b*SS + s1)*SS + s2] = acc[r][c][i];
            }
}

// ---------- softmax over batch axis; writes bf16 probs; zeroes stats ----------
__global__ __launch_bounds__(256) void k_softmax_b(
    const float* __restrict__ score, u16* __restrict__ scb,
    float* __restrict__ stats)
{
    int sid = blockIdx.x*256 + threadIdx.x;
    if (sid < 16384) stats[sid] = 0.0f;
    float vals[16];
    float m = -1e30f;
    #pragma unroll
    for (int b = 0; b < 16; ++b){
        vals[b] = score[(size_t)b*SS*SS + sid];
        m = fmaxf(m, vals[b]);
    }
    float sum = 0.f;
    #pragma unroll
    for (int b = 0; b < 16; ++b){ vals[b] = __expf(vals[b]-m); sum += vals[b]; }
    float inv = 1.0f/sum;
    #pragma unroll
    for (int b = 0; b < 16; ++b) scb[(size_t)b*SS*SS + sid] = bf16_rne(vals[b]*inv);
}

// ---------- o_pre = P*vT (128x128), gload_lds, K=128 per stage + fused LN stats ----------
__global__ __launch_bounds__(256) void k_sv_mfma(
    const u16* __restrict__ scb, const u16* __restrict__ vT,
    float* __restrict__ o, float* __restrict__ stats)
{
    int bid = XSWZ(blockIdx.x);           // 16b x 4 s1t x 8 dt = 512
    int b = bid >> 5;
    int s1_0 = ((bid >> 3) & 3) * 128;
    int d0 = (bid & 7) * 128;
    __shared__ u16 As[2*128*64], Bs[2*128*64];
    int tid = threadIdx.x;
    int w = tid >> 6, lane = tid & 63;
    int l15 = lane & 15, l4 = lane >> 4;
    f32x4 acc[2][8];
    #pragma unroll
    for (int r=0;r<2;++r)
        #pragma unroll
        for(int c=0;c<8;++c) acc[r][c] = (f32x4){0.f,0.f,0.f,0.f};

    const u16* aBase = scb + ((size_t)b*SS + s1_0)*SS;
    const u16* bBase = vT + ((size_t)b*1024 + d0)*SS;
    for (int st = 0; st < 8; st += 2){
        #pragma unroll
        for (int hhf = 0; hhf < 2; ++hhf){
            int s2b = (st + hhf)*64;
            #pragma unroll
            for (int i = 0; i < 4; ++i){
                int idx = tid + i*256;
                int r = idx >> 3, f = idx & 7;
                int fs = f ^ (r & 7);
                __builtin_amdgcn_global_load_lds(AS1C(aBase + (size_t)r*SS + s2b + fs*8),
                                                 AS3(&As[hhf*128*64 + idx*8]), 16, 0, 0);
                __builtin_amdgcn_global_load_lds(AS1C(bBase + (size_t)r*SS + s2b + fs*8),
                                                 AS3(&Bs[hhf*128*64 + idx*8]), 16, 0, 0);
            }
        }
        __syncthreads();
        #pragma unroll
        for (int hhf = 0; hhf < 2; ++hhf){
            #pragma unroll
            for (int ks = 0; ks < 2; ++ks){
                bf16x8 a0[2];
                #pragma unroll
                for (int r=0;r<2;++r){
                    int row = w*32 + r*16 + l15;
                    a0[r] = *(const bf16x8*)&As[hhf*128*64 + row*64 + (((ks*4 + l4) ^ (row & 7))*8)];
                }
                #pragma unroll
                for (int c=0;c<8;++c){
                    int row = c*16 + l15;
                    bf16x8 b0 = *(const bf16x8*)&Bs[hhf*128*64 + row*64 + (((ks*4 + l4) ^ (row & 7))*8)];
                    #pragma unroll
                    for (int r=0;r<2;++r)
                        acc[r][c] = __builtin_amdgcn_mfma_f32_16x16x32_bf16(a0[r], b0, acc[r][c],0,0,0);
                }
            }
        }
        __syncthreads();
    }
    #pragma unroll
    for (int r=0;r<2;++r)
        #pragma unroll
        for (int c=0;c<8;++c)
            #pragma unroll
            for (int i=0;i<4;++i){
                int s1 = s1_0 + w*32 + r*16 + l4*4 + i;
                o[((size_t)b*SS + s1)*1024 + d0 + c*16 + l15] = acc[r][c][i];
            }

    #pragma unroll
    for (int r=0;r<2;++r){
        #pragma unroll
        for (int i=0;i<4;++i){
            float s = 0.f, q = 0.f;
            #pragma unroll
            for (int c=0;c<8;++c){ float v = acc[r][c][i]; s += v; q += v*v; }
            #pragma unroll
            for (int m = 1; m <= 8; m <<= 1){
                s += __shfl_xor(s, m, 64);
                q += __shfl_xor(q, m, 64);
            }
            if (l15 == 0){
                int s1 = s1_0 + w*32 + r*16 + l4*4 + i;
                atomicAdd(&stats[2*((size_t)b*SS + s1)],     s);
                atomicAdd(&stats[2*((size_t)b*SS + s1) + 1], q);
            }
        }
    }
}

extern "C" void kernel_launch(void* const* d_in, const int* in_sizes, int n_in,
                              void* d_out, int out_size, void* d_ws, size_t ws_size,
                              hipStream_t stream)
{
    const int*   x    = (const int*)  d_in[0];
    const float* emb  = (const float*)d_in[1];
    const float* g0   = (const float*)d_in[2];
    const float* b0   = (const float*)d_in[3];
    const float* qw   = (const float*)d_in[4];
    const float* qb   = (const float*)d_in[5];
    const float* kw   = (const float*)d_in[6];
    const float* kb   = (const float*)d_in[7];
    const float* vw   = (const float*)d_in[8];
    const float* vb_  = (const float*)d_in[9];
    const float* lng  = (const float*)d_in[10];
    const float* lnb  = (const float*)d_in[11];
    const float* cw   = (const float*)d_in[12];
    const float* cb   = (const float*)d_in[13];
    float* out = (float*)d_out;

    const size_t TS = (size_t)16*16*512*64;       // 8388608
    u16* wsu = (u16*)d_ws;
    u16* hh = wsu + 0*TS;
    u16* hl = wsu + 1*TS;
    u16* qh = wsu + 2*TS;
    u16* ql = wsu + 3*TS;                         // hosts stats head only
    u16* kh = wsu + 4*TS;
    u16* kl = wsu + 5*TS;
    u16* vT = wsu + 6*TS;
    float* sc    = (float*)(wsu + 7*TS);          // 16*512*512 f32 = 1 slot
    u16*   scb   = qh;                            // qh dead after qk
    float* o_pre = (float*)(wsu + 4*TS);          // kh,kl dead after qk
    float* stats = (float*)ql;                    // ql slot head (16384 f32)
    u16* wprep = (u16*)((char*)d_ws + ((size_t)160 << 20));  // ws 640 MiB; prep at 160 MiB

    float* hbuf[5];
    hbuf[0] = out + 1*TS;
    hbuf[1] = out + 2*TS;
    hbuf[2] = out + 3*TS;
    hbuf[3] = out + 4*TS;
    hbuf[4] = out;

    k_prep<<<4, 256, 0, stream>>>(qw, kw, vw, cw, lng, lnb, wprep);
    k_embed_ln<<<8192, 256, 0, stream>>>(x, emb, g0, b0, hbuf[0], hh, hl);
    for (int i = 0; i < 4; ++i){
        const u16* wp = wprep + i*WPREP_STRIDE;
        k_conv_qkv<<<1024, 256, 0, stream>>>(
            hh, hl, wp, qb + i*16, kb + i*16, vb_ + i*16, qh, kh, kl, vT);
        k_qk_mfma<<<512, 256, 0, stream>>>(qh, kh, kl, sc);
        k_softmax_b<<<1024, 256, 0, stream>>>(sc, scb, stats);
        k_sv_mfma<<<512, 256, 0, stream>>>(scb, vT, o_pre, stats);
        k_conv_ln_res2<<<1024, 256, 0, stream>>>(
            o_pre, stats, wp, cb + i*16, hbuf[i], hbuf[i+1], hh, hl);
    }
}